// Round 4
// baseline (592.786 us; speedup 1.0000x reference)
//
#include <hip/hip_runtime.h>
#include <math.h>

#define NUM_HOP 3
#define VOCAB   32000
#define DIM     512
#define MEM     60
#define BS      64
#define STORY   50
#define SENT    32
#define QLEN    16

#define TBL     ((size_t)VOCAB * DIM)

typedef _Float16 v8h __attribute__((ext_vector_type(8)));   // 8 fp16
typedef float    v4f __attribute__((ext_vector_type(4)));

static __device__ __forceinline__ ushort f2h(float x) {
    union { _Float16 h; ushort u; } v;
    v.h = (_Float16)x;           // RNE f32->f16
    return v.u;
}

// ---------------------------------------------------------------------------
// u0[b,:] = sum_t A0[query[b,t]] (skip idx 0); emit U2h = fp16([u; u*ds]).
// grid: BS x 512
__global__ __launch_bounds__(512) void k_prep(const float* __restrict__ A0,
                                              const int*   __restrict__ query,
                                              float*       __restrict__ u,
                                              ushort*      __restrict__ U2h) {
    const int b = blockIdx.x, tid = threadIdx.x;
    const int* q = query + b * QLEN;
    int idx[QLEN];
    #pragma unroll
    for (int t = 0; t < QLEN; ++t) idx[t] = q[t];
    float acc = 0.f;
    #pragma unroll
    for (int t = 0; t < QLEN; ++t)
        if (idx[t] != 0) acc += A0[(size_t)idx[t] * DIM + tid];
    u[(size_t)b * DIM + tid] = acc;
    U2h[(size_t)b * DIM + tid] = f2h(acc);
    U2h[(size_t)(BS + b) * DIM + tid] = f2h(acc * (float)(tid + 1) * (1.0f / (float)DIM));
}

// ---------------------------------------------------------------------------
// U2h refresh after u-update. grid: BS x 512
__global__ __launch_bounds__(512) void k_uref(const float* __restrict__ u,
                                              ushort*      __restrict__ U2h) {
    const int b = blockIdx.x, tid = threadIdx.x;
    const float un = u[(size_t)b * DIM + tid];
    U2h[(size_t)b * DIM + tid] = f2h(un);
    U2h[(size_t)(BS + b) * DIM + tid] = f2h(un * (float)(tid + 1) * (1.0f / (float)DIM));
}

// ---------------------------------------------------------------------------
// Z[v][0..63] = A_h[v].u_b ; Z[v][64..127] = A_h[v].(u_b*ds)  (fp16 MFMA)
// ZERO LDS, ZERO BARRIERS. Each wave owns a 16-row x 64-col tile:
//   task = blk*4+wave; rt = task>>1 (row-tile), nh = task&1 (zu/zd half).
// A-frags straight from f32 table (32 B/lane, line-efficient); B-frags from
// L2-hot U2h (16 B/lane). rows >= VOCAB map to T_A (clamped).
__global__ __launch_bounds__(256) void k_z(const float*  __restrict__ Ah,
                                           const float*  __restrict__ T_A,
                                           const ushort* __restrict__ U2h,
                                           float*        __restrict__ Z) {
    const int tid  = threadIdx.x;
    const int lane = tid & 63;
    const int wave = tid >> 6;
    const int i16  = lane & 15;
    const int quad = lane >> 4;
    const int task = blockIdx.x * 4 + wave;     // 0..4007
    const int rt   = task >> 1;                 // 0..2003
    const int nh   = task & 1;
    const int row  = rt * 16 + i16;

    const float* arow;
    if (row < VOCAB) {
        arow = Ah + (size_t)row * DIM;
    } else {
        int t = row - VOCAB; if (t > MEM - 1) t = MEM - 1;
        arow = T_A + (size_t)t * DIM;
    }
    const ushort* ub = U2h + (size_t)(nh * 64) * DIM;

    v4f acc[4];
    #pragma unroll
    for (int nt = 0; nt < 4; ++nt) acc[nt] = (v4f){0.f, 0.f, 0.f, 0.f};

    #pragma unroll 4
    for (int ki = 0; ki < 16; ++ki) {
        const int k0 = ki * 32 + quad * 8;
        const float4 a0 = *(const float4*)(arow + k0);
        const float4 a1 = *(const float4*)(arow + k0 + 4);
        v8h af;
        af[0] = (_Float16)a0.x; af[1] = (_Float16)a0.y;
        af[2] = (_Float16)a0.z; af[3] = (_Float16)a0.w;
        af[4] = (_Float16)a1.x; af[5] = (_Float16)a1.y;
        af[6] = (_Float16)a1.z; af[7] = (_Float16)a1.w;
        #pragma unroll
        for (int nt = 0; nt < 4; ++nt) {
            const v8h bf = *(const v8h*)(ub + (size_t)(nt * 16 + i16) * DIM + k0);
            acc[nt] = __builtin_amdgcn_mfma_f32_16x16x32_f16(af, bf, acc[nt], 0, 0, 0);
        }
    }

    const int vb = rt * 16 + quad * 4;
    #pragma unroll
    for (int nt = 0; nt < 4; ++nt) {
        const int col = nh * 64 + nt * 16 + i16;
        #pragma unroll
        for (int r = 0; r < 4; ++r)
            Z[(size_t)(vb + r) * 128 + col] = acc[nt][r];
    }
}

// ---------------------------------------------------------------------------
// score[b,s] = sum_w (aw*zu - bw*zd) + TZ[s][b]; softmax over s -> p[b][s].
// grid: BS x 256 (4 waves, 2 sentences per wave-iter).
__global__ __launch_bounds__(256) void k_score(const int*   __restrict__ ctx,
                                               const float* __restrict__ Z,
                                               float*       __restrict__ p) {
    const int b    = blockIdx.x;
    const int tid  = threadIdx.x;
    const int wave = tid >> 6;
    const int lane = tid & 63;
    const int w    = lane & 31;
    const int half = lane >> 5;
    __shared__ float ss[64];

    const float aw = 1.0f - (float)(w + 1) * (1.0f / 32.0f);
    const float bw = 1.0f - (float)(w + 1) * (1.0f / 16.0f);

    #pragma unroll
    for (int i = 0; i < 7; ++i) {
        const int s = i * 8 + wave * 2 + half;
        float val = 0.f;
        if (s < STORY) {
            const int idx = ctx[b * (STORY * SENT) + s * SENT + w];
            if (idx != 0) {
                const float zu = Z[(size_t)idx * 128 + b];
                const float zd = Z[(size_t)idx * 128 + 64 + b];
                val = aw * zu - bw * zd;
            }
        }
        val += __shfl_down(val, 16); val += __shfl_down(val, 8);
        val += __shfl_down(val, 4);  val += __shfl_down(val, 2);
        val += __shfl_down(val, 1);
        if (w == 0 && s < STORY)
            ss[s] = val + Z[(size_t)(VOCAB + s) * 128 + b];   // + T_A[s].u_b
    }
    __syncthreads();

    if (tid < 64) {
        const float v = (tid < STORY) ? ss[tid] : -1e30f;
        float mx = v;
        for (int off = 32; off; off >>= 1) mx = fmaxf(mx, __shfl_down(mx, off));
        mx = __shfl(mx, 0);
        const float e = (tid < STORY) ? __expf(v - mx) : 0.f;
        float sm = e;
        for (int off = 32; off; off >>= 1) sm += __shfl_down(sm, off);
        sm = __shfl(sm, 0);
        p[b * 64 + tid] = e / sm;   // tid >= STORY stores 0
    }
}

// ---------------------------------------------------------------------------
// u[b] += sum_{s,w} p[b,s] * A_{h+1}[ctx[b,s,w]]  (atomicAdd into u).
// grid: BS*4 blocks (b, quarter of words) x 512 (8 waves x 50 words each).
__global__ __launch_bounds__(512) void k_cupd(const int*   __restrict__ ctx,
                                              const float* __restrict__ p,
                                              const float* __restrict__ An,
                                              float*       __restrict__ u) {
    const int b    = blockIdx.x >> 2;
    const int q    = blockIdx.x & 3;
    const int tid  = threadIdx.x;
    const int wave = tid >> 6;
    const int lane = tid & 63;
    const int d0   = lane * 8;
    __shared__ float ps[64];
    __shared__ float red[8][DIM];    // 16 KB

    if (tid < 64) ps[tid] = p[b * 64 + tid];
    __syncthreads();

    const int* cb = ctx + b * (STORY * SENT);
    float acc[8];
    #pragma unroll
    for (int j = 0; j < 8; ++j) acc[j] = 0.f;

    const int base = q * 400 + wave * 50;
    #pragma unroll 5
    for (int i = 0; i < 50; ++i) {
        const int t = base + i;
        const int idx = cb[t];
        const float pw = (idx != 0) ? ps[t >> 5] : 0.f;
        const float* row = An + (size_t)idx * DIM + d0;
        const float4 r0 = *(const float4*)(row);
        const float4 r1 = *(const float4*)(row + 4);
        acc[0] = fmaf(pw, r0.x, acc[0]); acc[1] = fmaf(pw, r0.y, acc[1]);
        acc[2] = fmaf(pw, r0.z, acc[2]); acc[3] = fmaf(pw, r0.w, acc[3]);
        acc[4] = fmaf(pw, r1.x, acc[4]); acc[5] = fmaf(pw, r1.y, acc[5]);
        acc[6] = fmaf(pw, r1.z, acc[6]); acc[7] = fmaf(pw, r1.w, acc[7]);
    }
    #pragma unroll
    for (int j = 0; j < 8; ++j) red[wave][d0 + j] = acc[j];
    __syncthreads();

    float s = 0.f;
    #pragma unroll
    for (int wv = 0; wv < 8; ++wv) s += red[wv][tid];
    atomicAdd(&u[(size_t)b * DIM + tid], s);
}

// ---------------------------------------------------------------------------
// logits = u @ A3^T via fp16 MFMA 16x16x32 (A3 converted inline, U2h plane 0).
// grid 500 x 256. v=0 forced to 0 (ref zeroes padding row).
__global__ __launch_bounds__(256) void k_logits(const float*  __restrict__ A3,
                                                const ushort* __restrict__ U2h,
                                                float*        __restrict__ out) {
    __shared__ ushort Abf[64 * 128];  // 16 KB
    __shared__ ushort Ubf[64 * 128];  // 16 KB
    const int tid  = threadIdx.x;
    const int lane = tid & 63;
    const int wave = tid >> 6;
    const int i16  = lane & 15;
    const int quad = lane >> 4;
    const int row0 = blockIdx.x * 64;

    v4f acc[4];
    #pragma unroll
    for (int nt = 0; nt < 4; ++nt) acc[nt] = (v4f){0.f, 0.f, 0.f, 0.f};

    for (int ko = 0; ko < 4; ++ko) {
        __syncthreads();
        #pragma unroll
        for (int it = 0; it < 4; ++it) {
            const int i = it * 256 + tid;
            const int r = i >> 4, g = i & 15;
            const float* src = A3 + ((size_t)(row0 + r)) * DIM + ko * 128 + g * 8;
            const float4 f0 = *(const float4*)(src);
            const float4 f1 = *(const float4*)(src + 4);
            union { ushort h[8]; uint4 q; } pk;
            pk.h[0] = f2h(f0.x); pk.h[1] = f2h(f0.y);
            pk.h[2] = f2h(f0.z); pk.h[3] = f2h(f0.w);
            pk.h[4] = f2h(f1.x); pk.h[5] = f2h(f1.y);
            pk.h[6] = f2h(f1.z); pk.h[7] = f2h(f1.w);
            *(uint4*)(&Abf[r * 128 + ((g ^ (r & 7)) * 8)]) = pk.q;
        }
        #pragma unroll
        for (int it = 0; it < 4; ++it) {
            const int i = it * 256 + tid;
            const int n = i >> 4, g = i & 15;
            const uint4 v = *(const uint4*)(U2h + (size_t)n * DIM + ko * 128 + g * 8);
            *(uint4*)(&Ubf[n * 128 + ((g ^ (n & 7)) * 8)]) = v;
        }
        __syncthreads();

        const int arow = wave * 16 + i16;
        #pragma unroll
        for (int ki = 0; ki < 4; ++ki) {
            const int ga = ki * 4 + quad;
            const v8h a = *(const v8h*)(&Abf[arow * 128 + ((ga ^ (arow & 7)) * 8)]);
            #pragma unroll
            for (int nt = 0; nt < 4; ++nt) {
                const int n = nt * 16 + i16;
                const v8h bb = *(const v8h*)(&Ubf[n * 128 + ((ga ^ (n & 7)) * 8)]);
                acc[nt] = __builtin_amdgcn_mfma_f32_16x16x32_f16(a, bb, acc[nt], 0, 0, 0);
            }
        }
    }

    const int vbase = row0 + wave * 16 + quad * 4;
    if (vbase == 0) {   // padding row v=0: logits[:,0] = 0
        #pragma unroll
        for (int nt = 0; nt < 4; ++nt) acc[nt][0] = 0.f;
    }
    #pragma unroll
    for (int nt = 0; nt < 4; ++nt) {
        const int bcol = nt * 16 + i16;
        #pragma unroll
        for (int r = 0; r < 4; ++r)
            out[(size_t)bcol * VOCAB + vbase + r] = acc[nt][r];
    }
}

// ---------------------------------------------------------------------------
// in-place row softmax over VOCAB; row cached in registers, exp computed once.
__global__ __launch_bounds__(1024) void k_vsm(float* __restrict__ out) {
    const int b   = blockIdx.x;
    const int tid = threadIdx.x;
    float* row = out + (size_t)b * VOCAB;
    __shared__ float red[16];
    __shared__ float bc;

    float x[32];
    #pragma unroll
    for (int k = 0; k < 31; ++k) x[k] = row[tid + k * 1024];
    const bool extra = (tid < VOCAB - 31 * 1024);
    x[31] = extra ? row[tid + 31 * 1024] : -1e30f;

    float mx = -1e30f;
    #pragma unroll
    for (int k = 0; k < 32; ++k) mx = fmaxf(mx, x[k]);
    for (int off = 32; off; off >>= 1) mx = fmaxf(mx, __shfl_down(mx, off));
    if ((tid & 63) == 0) red[tid >> 6] = mx;
    __syncthreads();
    if (tid < 64) {
        float v = (tid < 16) ? red[tid] : -1e30f;
        for (int off = 8; off; off >>= 1) v = fmaxf(v, __shfl_down(v, off));
        if (tid == 0) bc = v;
    }
    __syncthreads();
    mx = bc;
    __syncthreads();

    float sum = 0.f;
    #pragma unroll
    for (int k = 0; k < 32; ++k) { x[k] = __expf(x[k] - mx); sum += x[k]; }
    if (!extra) sum -= x[31];
    for (int off = 32; off; off >>= 1) sum += __shfl_down(sum, off);
    if ((tid & 63) == 0) red[tid >> 6] = sum;
    __syncthreads();
    if (tid < 64) {
        float v = (tid < 16) ? red[tid] : 0.f;
        for (int off = 8; off; off >>= 1) v += __shfl_down(v, off);
        if (tid == 0) bc = v;
    }
    __syncthreads();
    const float inv = 1.0f / bc;

    #pragma unroll
    for (int k = 0; k < 31; ++k) row[tid + k * 1024] = x[k] * inv;
    if (extra) row[tid + 31 * 1024] = x[31] * inv;
}

// ---------------------------------------------------------------------------
extern "C" void kernel_launch(void* const* d_in, const int* in_sizes, int n_in,
                              void* d_out, int out_size, void* d_ws, size_t ws_size,
                              hipStream_t stream) {
    const int*   ctx   = (const int*)d_in[0];    // (BS, STORY, SENT)
    const int*   query = (const int*)d_in[1];    // (BS, QLEN)
    const float* A     = (const float*)d_in[2];  // (4, VOCAB, DIM)
    const float* T_A   = (const float*)d_in[3];  // (1, MEM, DIM)
    float* out = (float*)d_out;                  // (BS, VOCAB)

    float*  u   = (float*)d_ws;                      // 64*512 f32
    ushort* U2h = (ushort*)(u + BS * DIM);           // 128*512 fp16
    float*  p   = (float*)(U2h + 2 * BS * DIM);      // 64*64 f32
    float*  Z   = p + BS * 64;                       // 32064*128 f32 (~16.4 MB)

    k_prep<<<BS, DIM, 0, stream>>>(A, query, u, U2h);
    for (int h = 0; h < NUM_HOP; ++h) {
        k_z    <<<1002, 256, 0, stream>>>(A + (size_t)h * TBL, T_A, U2h, Z);
        k_score<<<BS, 256, 0, stream>>>(ctx, Z, p);
        k_cupd <<<BS * 4, 512, 0, stream>>>(ctx, p, A + (size_t)(h + 1) * TBL, u);
        k_uref <<<BS, 512, 0, stream>>>(u, U2h);
    }
    k_logits<<<500, 256, 0, stream>>>(A + 3 * TBL, U2h, out);
    k_vsm  <<<BS, 1024, 0, stream>>>(out);
}